// Round 9
// baseline (37.399 us; speedup 1.0000x reference)
//
#include <hip/hip_runtime.h>

typedef __attribute__((ext_vector_type(8))) short bf16x8;
typedef __attribute__((ext_vector_type(4))) float f32x4;

#define C_DIM 512
#define HID   256
#define B_DIM 8
#define L_DIM 196
#define MROWS (B_DIM*L_DIM)     // 1568 = 49*32, exact
#define MT    32                // rows per block (2 m-frags of 16)
#define NLT   (MROWS/MT)        // 49 m-tiles
#define KSTEP (C_DIM/32)        // 16 k-steps of 32
#define ROWS  14                // i-rows per block (phase 2, shared by 4 waves)
#define NIG   (L_DIM/ROWS)      // 14 i-groups
#define JCL   7                 // j per chunk (phase 2)
#define NJC   (L_DIM/JCL)       // 28 j-chunks
#define NJCG  (NJC/4)           // 7 chunk-groups (4 chunks = 4 waves per block)
#define PAIR_BLOCKS (B_DIM*NIG*NJCG)        // 784
#define P_ELEMS        (B_DIM*L_DIM*HID)
#define PARTIAL_ELEMS  (B_DIM*NJC*L_DIM)    // 43904

// f32 -> bf16 bits, round-to-nearest (ties up): 2 VALU ops
__device__ __forceinline__ short bf16r(float x) {
  unsigned u = __builtin_bit_cast(unsigned, x);
  return (short)((u + 0x8000u) >> 16);
}

// Phase 1 (r8 exact): MFMA bf16, on-the-fly conversion.
//   p[r,h] = sum_c f[b(r),c,l(r)] * W[c,h]   (+ b1[h] for side 0)
__global__ __launch_bounds__(64) void gemm_p_mfma(
    const float* __restrict__ f1, const float* __restrict__ f2,
    const float* __restrict__ W1, const float* __restrict__ b1,
    float* __restrict__ p1, float* __restrict__ p2) {
  const int side = blockIdx.y;
  const int lt = blockIdx.x % NLT;              // m-tile
  const int ht = blockIdx.x / NLT;              // 0..3 (64 h each)
  const float* __restrict__ f = side ? f2 : f1;
  const float* __restrict__ W = W1 + side * C_DIM * HID;
  float* __restrict__ p = side ? p2 : p1;

  const int lane = threadIdx.x;
  const int g    = lane >> 4;                   // k-chunk group 0..3
  const int mcol = lane & 15;

  int aoff[2];
  #pragma unroll
  for (int mi = 0; mi < 2; ++mi) {
    const int r = lt * MT + mi * 16 + mcol;
    const int b = r / L_DIM;
    const int l = r - b * L_DIM;
    aoff[mi] = (b * C_DIM) * L_DIM + l;
  }
  const int h0 = ht * 64 + mcol;

  f32x4 acc[2][4];
  #pragma unroll
  for (int mi = 0; mi < 2; ++mi)
    #pragma unroll
    for (int ni = 0; ni < 4; ++ni)
      acc[mi][ni] = (f32x4){0.f, 0.f, 0.f, 0.f};

  for (int ks = 0; ks < KSTEP; ++ks) {
    const int k0 = ks * 32 + g * 8;
    bf16x8 afr[2], bfr[4];
    #pragma unroll
    for (int mi = 0; mi < 2; ++mi) {
      const float* __restrict__ pa = f + aoff[mi] + k0 * L_DIM;
      #pragma unroll
      for (int i = 0; i < 8; ++i) afr[mi][i] = bf16r(pa[i * L_DIM]);
    }
    #pragma unroll
    for (int ni = 0; ni < 4; ++ni) {
      const float* __restrict__ pb = W + k0 * HID + h0 + ni * 16;
      #pragma unroll
      for (int i = 0; i < 8; ++i) bfr[ni][i] = bf16r(pb[i * HID]);
    }
    #pragma unroll
    for (int mi = 0; mi < 2; ++mi)
      #pragma unroll
      for (int ni = 0; ni < 4; ++ni)
        acc[mi][ni] = __builtin_amdgcn_mfma_f32_16x16x32_bf16(
            afr[mi], bfr[ni], acc[mi][ni], 0, 0, 0);
  }

  #pragma unroll
  for (int mi = 0; mi < 2; ++mi) {
    const int r0 = lt * MT + mi * 16 + g * 4;
    #pragma unroll
    for (int ni = 0; ni < 4; ++ni) {
      const int h = h0 + ni * 16;
      const float bias = side ? 0.0f : b1[h];
      #pragma unroll
      for (int reg = 0; reg < 4; ++reg)
        p[(r0 + reg) * HID + h] = acc[mi][ni][reg] + bias;
    }
  }
}

// Phase 2 v2: block = 4 waves sharing one 14-i-row group (L1-shared a-loads);
// wave w takes j-chunk jc = jcg*4+w (7 j's).
// partial[b,jc,i] = sum_{j in chunk jc} relu(p1[b,i,:]+p2[b,j,:]).W2
// grid = 8*14*7 = 784 blocks of 256 -> 3136 waves (~3/SIMD).
__global__ __launch_bounds__(256) void pair_kernel(
    const float* __restrict__ p1, const float* __restrict__ p2,
    const float* __restrict__ W2, float* __restrict__ partial) {
  const int lane = threadIdx.x & 63;
  const int w    = threadIdx.x >> 6;            // 0..3
  const int b    = blockIdx.x / (NIG * NJCG);
  const int rem  = blockIdx.x % (NIG * NJCG);
  const int ig   = rem / NJCG;                  // 0..13 (i-group, block-shared)
  const int jcg  = rem % NJCG;                  // 0..6
  const int jc   = jcg * 4 + w;                 // 0..27 (per-wave j-chunk)

  const float4 wv = *(const float4*)(W2 + lane * 4);
  const float* __restrict__ p1b = p1 + (b * L_DIM + ig * ROWS) * HID + lane * 4;

  float4 a[ROWS];                               // 14 contiguous i-rows
  #pragma unroll
  for (int k = 0; k < ROWS; ++k)
    a[k] = *(const float4*)(p1b + k * HID);

  float s[ROWS];
  #pragma unroll
  for (int k = 0; k < ROWS; ++k) s[k] = 0.0f;

  const float4* __restrict__ vp =
      (const float4*)(p2 + (b * L_DIM + jc * JCL) * HID) + lane;

#define PAIR_BODY(vv)                                            \
  {                                                              \
    _Pragma("unroll")                                            \
    for (int k = 0; k < ROWS; ++k) {                             \
      s[k] = fmaf(fmaxf(a[k].x + (vv).x, 0.f), wv.x, s[k]);      \
      s[k] = fmaf(fmaxf(a[k].y + (vv).y, 0.f), wv.y, s[k]);      \
      s[k] = fmaf(fmaxf(a[k].z + (vv).z, 0.f), wv.z, s[k]);      \
      s[k] = fmaf(fmaxf(a[k].w + (vv).w, 0.f), wv.w, s[k]);      \
    }                                                            \
  }

  float4 v = vp[0];
  #pragma unroll
  for (int j = 0; j < JCL - 1; ++j) {           // branch-free preload pipeline
    float4 vn = vp[(j + 1) * (HID / 4)];
    PAIR_BODY(v);
    v = vn;
  }
  PAIR_BODY(v);
#undef PAIR_BODY

  #pragma unroll
  for (int off = 32; off > 0; off >>= 1) {
    #pragma unroll
    for (int k = 0; k < ROWS; ++k) s[k] += __shfl_down(s[k], off);
  }
  if (lane == 0) {
    float* pp = partial + (b * NJC + jc) * L_DIM + ig * ROWS;
    #pragma unroll
    for (int k = 0; k < ROWS; ++k) pp[k] = s[k];
  }
}

// Phase 3: out[b] = sum over NJC*L partials + L*L*b2
__global__ __launch_bounds__(256) void reduce_kernel(
    const float* __restrict__ partial, const float* __restrict__ b2,
    float* __restrict__ out) {
  const int b = blockIdx.x;
  const int t = threadIdx.x;
  float acc = 0.0f;
  for (int idx = t; idx < NJC * L_DIM; idx += 256)
    acc += partial[b * NJC * L_DIM + idx];
  #pragma unroll
  for (int off = 32; off > 0; off >>= 1) acc += __shfl_down(acc, off);
  __shared__ float sred[4];
  if ((t & 63) == 0) sred[t >> 6] = acc;
  __syncthreads();
  if (t == 0)
    out[b] = sred[0] + sred[1] + sred[2] + sred[3]
           + (float)(L_DIM * L_DIM) * b2[0];
}

extern "C" void kernel_launch(void* const* d_in, const int* in_sizes, int n_in,
                              void* d_out, int out_size, void* d_ws, size_t ws_size,
                              hipStream_t stream) {
  const float* f1 = (const float*)d_in[0];   // [B, C, 14, 14]
  const float* f2 = (const float*)d_in[1];
  const float* W1 = (const float*)d_in[2];   // [2C, HID]
  const float* b1 = (const float*)d_in[3];   // [HID]
  const float* W2 = (const float*)d_in[4];   // [HID, 1]
  const float* b2 = (const float*)d_in[5];   // [1]
  float* out = (float*)d_out;                // [B, 1]

  float* p1      = (float*)d_ws;
  float* p2      = p1 + P_ELEMS;
  float* partial = p2 + P_ELEMS;

  dim3 g1(NLT * 4, 2);                       // (49 m-tiles x 4 h-tiles, 2 sides)
  gemm_p_mfma<<<g1, 64, 0, stream>>>(f1, f2, W1, b1, p1, p2);

  pair_kernel<<<PAIR_BLOCKS, 256, 0, stream>>>(p1, p2, W2, partial);

  reduce_kernel<<<B_DIM, 256, 0, stream>>>(partial, b2, out);
}

// Round 10
// 32.804 us; speedup vs baseline: 1.1401x; 1.1401x over previous
//
#include <hip/hip_runtime.h>

typedef __attribute__((ext_vector_type(8))) short bf16x8;
typedef __attribute__((ext_vector_type(4))) float f32x4;

#define C_DIM 512
#define HID   256
#define B_DIM 8
#define L_DIM 196
#define MROWS (B_DIM*L_DIM)     // 1568 = 49*32, exact
#define MT    32                // rows per block (2 m-frags of 16)
#define NLT   (MROWS/MT)        // 49 m-tiles
#define KSTEP (C_DIM/32)        // 16 k-steps of 32
#define ROWS  14                // i-rows per wave (phase 2)
#define LT    14
#define NJC   14                // j-chunks (phase 2)
#define JCL   (L_DIM/NJC)       // 14
#define PAIR_BLOCKS ((B_DIM*NJC*LT)/4)      // 392
#define P_ELEMS (B_DIM*L_DIM*HID)

// f32 -> bf16 bits, round-to-nearest (ties up): 2 VALU ops
__device__ __forceinline__ short bf16r(float x) {
  unsigned u = __builtin_bit_cast(unsigned, x);
  return (short)((u + 0x8000u) >> 16);
}

// Phase 1 (r8 exact + out-init): MFMA bf16, on-the-fly conversion.
//   p[r,h] = sum_c f[b(r),c,l(r)] * W[c,h]   (+ b1[h] for side 0)
__global__ __launch_bounds__(64) void gemm_p_mfma(
    const float* __restrict__ f1, const float* __restrict__ f2,
    const float* __restrict__ W1, const float* __restrict__ b1,
    const float* __restrict__ b2,
    float* __restrict__ p1, float* __restrict__ p2,
    float* __restrict__ out) {
  // init output accumulators (pair_kernel atomicAdds into them; stream order
  // guarantees this kernel completes -- and its writes are visible -- first)
  if (blockIdx.x == 0 && blockIdx.y == 0 && threadIdx.x < B_DIM)
    out[threadIdx.x] = (float)(L_DIM * L_DIM) * b2[0];

  const int side = blockIdx.y;
  const int lt = blockIdx.x % NLT;              // m-tile
  const int ht = blockIdx.x / NLT;              // 0..3 (64 h each)
  const float* __restrict__ f = side ? f2 : f1;
  const float* __restrict__ W = W1 + side * C_DIM * HID;
  float* __restrict__ p = side ? p2 : p1;

  const int lane = threadIdx.x;
  const int g    = lane >> 4;                   // k-chunk group 0..3
  const int mcol = lane & 15;

  int aoff[2];
  #pragma unroll
  for (int mi = 0; mi < 2; ++mi) {
    const int r = lt * MT + mi * 16 + mcol;
    const int b = r / L_DIM;
    const int l = r - b * L_DIM;
    aoff[mi] = (b * C_DIM) * L_DIM + l;
  }
  const int h0 = ht * 64 + mcol;

  f32x4 acc[2][4];
  #pragma unroll
  for (int mi = 0; mi < 2; ++mi)
    #pragma unroll
    for (int ni = 0; ni < 4; ++ni)
      acc[mi][ni] = (f32x4){0.f, 0.f, 0.f, 0.f};

  for (int ks = 0; ks < KSTEP; ++ks) {
    const int k0 = ks * 32 + g * 8;
    bf16x8 afr[2], bfr[4];
    #pragma unroll
    for (int mi = 0; mi < 2; ++mi) {
      const float* __restrict__ pa = f + aoff[mi] + k0 * L_DIM;
      #pragma unroll
      for (int i = 0; i < 8; ++i) afr[mi][i] = bf16r(pa[i * L_DIM]);
    }
    #pragma unroll
    for (int ni = 0; ni < 4; ++ni) {
      const float* __restrict__ pb = W + k0 * HID + h0 + ni * 16;
      #pragma unroll
      for (int i = 0; i < 8; ++i) bfr[ni][i] = bf16r(pb[i * HID]);
    }
    #pragma unroll
    for (int mi = 0; mi < 2; ++mi)
      #pragma unroll
      for (int ni = 0; ni < 4; ++ni)
        acc[mi][ni] = __builtin_amdgcn_mfma_f32_16x16x32_bf16(
            afr[mi], bfr[ni], acc[mi][ni], 0, 0, 0);
  }

  #pragma unroll
  for (int mi = 0; mi < 2; ++mi) {
    const int r0 = lt * MT + mi * 16 + g * 4;
    #pragma unroll
    for (int ni = 0; ni < 4; ++ni) {
      const int h = h0 + ni * 16;
      const float bias = side ? 0.0f : b1[h];
      #pragma unroll
      for (int reg = 0; reg < 4; ++reg)
        p[(r0 + reg) * HID + h] = acc[mi][ni][reg] + bias;
    }
  }
}

// Phase 2 (r8 tiling) + fused total-reduction:
//   block-sum of relu(p1[b,i,:]+p2[b,j,:]).W2 over its (i,j) range,
//   then ONE atomicAdd per block into out[b]. No partial buffer, no kernel 3.
// wave = 14 i-rows x one 14-j chunk; 392 blocks of 256.
__global__ __launch_bounds__(256) void pair_kernel(
    const float* __restrict__ p1, const float* __restrict__ p2,
    const float* __restrict__ W2, float* __restrict__ out) {
  const int lane = threadIdx.x & 63;
  const int w    = threadIdx.x >> 6;
  const int wid  = blockIdx.x * 4 + w;          // 0..1567
  const int b  = wid / (NJC * LT);              // block-uniform (49 blocks/b)
  const int r  = wid % (NJC * LT);
  const int jc = r / LT;                        // 0..13
  const int wi = r % LT;                        // 0..13

  const float4 wv = *(const float4*)(W2 + lane * 4);
  const float* __restrict__ p1b = p1 + (b * L_DIM) * HID + lane * 4;

  float4 a[ROWS];
  #pragma unroll
  for (int k = 0; k < ROWS; ++k)
    a[k] = *(const float4*)(p1b + (wi + k * LT) * HID);   // i = wi + k*14

  float s[ROWS];
  #pragma unroll
  for (int k = 0; k < ROWS; ++k) s[k] = 0.0f;

  const float4* __restrict__ vp =
      (const float4*)(p2 + (b * L_DIM + jc * JCL) * HID) + lane;

#define PAIR_BODY(vv)                                            \
  {                                                              \
    _Pragma("unroll")                                            \
    for (int k = 0; k < ROWS; ++k) {                             \
      s[k] = fmaf(fmaxf(a[k].x + (vv).x, 0.f), wv.x, s[k]);      \
      s[k] = fmaf(fmaxf(a[k].y + (vv).y, 0.f), wv.y, s[k]);      \
      s[k] = fmaf(fmaxf(a[k].z + (vv).z, 0.f), wv.z, s[k]);      \
      s[k] = fmaf(fmaxf(a[k].w + (vv).w, 0.f), wv.w, s[k]);      \
    }                                                            \
  }

  float4 v = vp[0];
  #pragma unroll
  for (int j = 0; j < JCL - 1; ++j) {           // branch-free preload pipeline
    float4 vn = vp[(j + 1) * (HID / 4)];
    PAIR_BODY(v);
    v = vn;
  }
  PAIR_BODY(v);
#undef PAIR_BODY

  // collapse rows first (13 adds), then one 6-step wave reduce
  float t = 0.0f;
  #pragma unroll
  for (int k = 0; k < ROWS; ++k) t += s[k];
  #pragma unroll
  for (int off = 32; off > 0; off >>= 1) t += __shfl_down(t, off);

  __shared__ float sred[4];
  if (lane == 0) sred[w] = t;
  __syncthreads();
  if (threadIdx.x == 0)
    atomicAdd(&out[b], sred[0] + sred[1] + sred[2] + sred[3]);  // 392 total
}

extern "C" void kernel_launch(void* const* d_in, const int* in_sizes, int n_in,
                              void* d_out, int out_size, void* d_ws, size_t ws_size,
                              hipStream_t stream) {
  const float* f1 = (const float*)d_in[0];   // [B, C, 14, 14]
  const float* f2 = (const float*)d_in[1];
  const float* W1 = (const float*)d_in[2];   // [2C, HID]
  const float* b1 = (const float*)d_in[3];   // [HID]
  const float* W2 = (const float*)d_in[4];   // [HID, 1]
  const float* b2 = (const float*)d_in[5];   // [1]
  float* out = (float*)d_out;                // [B, 1]

  float* p1 = (float*)d_ws;
  float* p2 = p1 + P_ELEMS;

  dim3 g1(NLT * 4, 2);                       // (49 m-tiles x 4 h-tiles, 2 sides)
  gemm_p_mfma<<<g1, 64, 0, stream>>>(f1, f2, W1, b1, b2, p1, p2, out);

  pair_kernel<<<PAIR_BLOCKS, 256, 0, stream>>>(p1, p2, W2, out);
}

// Round 11
// 31.693 us; speedup vs baseline: 1.1800x; 1.0351x over previous
//
#include <hip/hip_runtime.h>

typedef __attribute__((ext_vector_type(8))) short bf16x8;
typedef __attribute__((ext_vector_type(4))) float f32x4;

#define C_DIM 512
#define HID   256
#define B_DIM 8
#define L_DIM 196
#define MROWS (B_DIM*L_DIM)     // 1568 = 49*32, exact
#define MT    32                // m rows per tile
#define NLT   (MROWS/MT)        // 49 m-tiles
#define NT    32                // n cols per tile
#define NNT   (HID/NT)          // 8 n-tiles
#define ROWS  14                // i-rows per wave (phase 2)
#define LT    14
#define NJC   14                // j-chunks (phase 2)
#define JCL   (L_DIM/NJC)       // 14
#define PAIR_BLOCKS ((B_DIM*NJC*LT)/4)      // 392
#define P_ELEMS (B_DIM*L_DIM*HID)

// f32 -> bf16 bits, round-to-nearest (ties up): 2 VALU ops
__device__ __forceinline__ short bf16r(float x) {
  unsigned u = __builtin_bit_cast(unsigned, x);
  return (short)((u + 0x8000u) >> 16);
}

// Phase 1 v3: MFMA bf16, K-split x4 for wave-count (3136 waves = 3/SIMD).
//   p[r,h] = sum_c f[b(r),c,l(r)] * W[c,h]   (+ b1[h] for side 0)
// Block = 256 thr = 4 waves = 4 k-quarters of ONE 32m x 32n tile.
// Per wave: 4 ksteps x (32 scalar loads -> cvt -> 4 MFMA); LDS tree-combine.
// Grid = (49 m-tiles x 8 n-tiles, 2 sides) = 784 blocks.
__global__ __launch_bounds__(256) void gemm_p_mfma(
    const float* __restrict__ f1, const float* __restrict__ f2,
    const float* __restrict__ W1, const float* __restrict__ b1,
    const float* __restrict__ b2,
    float* __restrict__ p1, float* __restrict__ p2,
    float* __restrict__ out) {
  // init output accumulators (pair_kernel atomicAdds into them)
  if (blockIdx.x == 0 && blockIdx.y == 0 && threadIdx.x < B_DIM)
    out[threadIdx.x] = (float)(L_DIM * L_DIM) * b2[0];

  const int side = blockIdx.y;
  const int lt = blockIdx.x >> 3;               // 0..48 m-tile
  const int nt = blockIdx.x & 7;                // 0..7  n-tile
  const float* __restrict__ f = side ? f2 : f1;
  const float* __restrict__ W = W1 + side * C_DIM * HID;
  float* __restrict__ p = side ? p2 : p1;

  const int tid  = threadIdx.x;
  const int kq   = tid >> 6;                    // wave = k-quarter 0..3
  const int lane = tid & 63;
  const int g    = lane >> 4;                   // k-subgroup 0..3
  const int mcol = lane & 15;

  int aoff[2];
  #pragma unroll
  for (int mi = 0; mi < 2; ++mi) {
    const int r = lt * MT + mi * 16 + mcol;     // < 1568
    const int b = r / L_DIM;
    const int l = r - b * L_DIM;
    aoff[mi] = (b * C_DIM) * L_DIM + l;
  }
  const int h0 = nt * NT + mcol;                // + ni*16

  f32x4 acc[2][2];
  #pragma unroll
  for (int mi = 0; mi < 2; ++mi)
    #pragma unroll
    for (int ni = 0; ni < 2; ++ni)
      acc[mi][ni] = (f32x4){0.f, 0.f, 0.f, 0.f};

  #pragma unroll
  for (int ks = 0; ks < 4; ++ks) {
    const int k0 = kq * 128 + ks * 32 + g * 8;  // this lane's 8 k's
    bf16x8 afr[2], bfr[2];
    #pragma unroll
    for (int mi = 0; mi < 2; ++mi) {
      const float* __restrict__ pa = f + aoff[mi] + k0 * L_DIM;
      #pragma unroll
      for (int i = 0; i < 8; ++i) afr[mi][i] = bf16r(pa[i * L_DIM]);
    }
    #pragma unroll
    for (int ni = 0; ni < 2; ++ni) {
      const float* __restrict__ pb = W + k0 * HID + h0 + ni * 16;
      #pragma unroll
      for (int i = 0; i < 8; ++i) bfr[ni][i] = bf16r(pb[i * HID]);
    }
    #pragma unroll
    for (int mi = 0; mi < 2; ++mi)
      #pragma unroll
      for (int ni = 0; ni < 2; ++ni)
        acc[mi][ni] = __builtin_amdgcn_mfma_f32_16x16x32_bf16(
            afr[mi], bfr[ni], acc[mi][ni], 0, 0, 0);
  }

  // tree-combine 4 k-quarter waves (flattened idx = mi*8 + ni*4 + reg)
  __shared__ float comb[2][64][17];             // 8.7 KB, 17-stride
  if (kq >= 2) {
    #pragma unroll
    for (int mi = 0; mi < 2; ++mi)
      #pragma unroll
      for (int ni = 0; ni < 2; ++ni)
        *(float4*)&comb[kq - 2][lane][mi * 8 + ni * 4] =
            *(float4*)&acc[mi][ni];
  }
  __syncthreads();
  if (kq < 2) {
    #pragma unroll
    for (int mi = 0; mi < 2; ++mi)
      #pragma unroll
      for (int ni = 0; ni < 2; ++ni) {
        const float4 o = *(const float4*)&comb[kq][lane][mi * 8 + ni * 4];
        acc[mi][ni][0] += o.x; acc[mi][ni][1] += o.y;
        acc[mi][ni][2] += o.z; acc[mi][ni][3] += o.w;
      }
  }
  __syncthreads();
  if (kq == 1) {
    #pragma unroll
    for (int mi = 0; mi < 2; ++mi)
      #pragma unroll
      for (int ni = 0; ni < 2; ++ni)
        *(float4*)&comb[0][lane][mi * 8 + ni * 4] = *(float4*)&acc[mi][ni];
  }
  __syncthreads();
  if (kq == 0) {
    // C/D layout (verified): col = lane&15, row = g*4 + reg
    #pragma unroll
    for (int mi = 0; mi < 2; ++mi) {
      const int r0 = lt * MT + mi * 16 + g * 4;
      #pragma unroll
      for (int ni = 0; ni < 2; ++ni) {
        const int h = h0 + ni * 16;
        const float bias = side ? 0.0f : b1[h];
        const float4 o = *(const float4*)&comb[0][lane][mi * 8 + ni * 4];
        p[(r0 + 0) * HID + h] = acc[mi][ni][0] + o.x + bias;
        p[(r0 + 1) * HID + h] = acc[mi][ni][1] + o.y + bias;
        p[(r0 + 2) * HID + h] = acc[mi][ni][2] + o.z + bias;
        p[(r0 + 3) * HID + h] = acc[mi][ni][3] + o.w + bias;
      }
    }
  }
}

// Phase 2 (r10 + 7-deep v-preload): wave = 14 i-rows x one 14-j chunk.
// Block-sum -> ONE atomicAdd per block into out[b]. 392 blocks of 256.
__global__ __launch_bounds__(256) void pair_kernel(
    const float* __restrict__ p1, const float* __restrict__ p2,
    const float* __restrict__ W2, float* __restrict__ out) {
  const int lane = threadIdx.x & 63;
  const int w    = threadIdx.x >> 6;
  const int wid  = blockIdx.x * 4 + w;          // 0..1567
  const int b  = wid / (NJC * LT);              // block-uniform
  const int r  = wid % (NJC * LT);
  const int jc = r / LT;                        // 0..13
  const int wi = r % LT;                        // 0..13

  const float4 wv = *(const float4*)(W2 + lane * 4);
  const float* __restrict__ p1b = p1 + (b * L_DIM) * HID + lane * 4;

  float4 a[ROWS];
  #pragma unroll
  for (int k = 0; k < ROWS; ++k)
    a[k] = *(const float4*)(p1b + (wi + k * LT) * HID);   // i = wi + k*14

  float s[ROWS];
  #pragma unroll
  for (int k = 0; k < ROWS; ++k) s[k] = 0.0f;

  const float4* __restrict__ vp =
      (const float4*)(p2 + (b * L_DIM + jc * JCL) * HID) + lane;

#define PAIR_BODY(vv)                                            \
  {                                                              \
    _Pragma("unroll")                                            \
    for (int k = 0; k < ROWS; ++k) {                             \
      s[k] = fmaf(fmaxf(a[k].x + (vv).x, 0.f), wv.x, s[k]);      \
      s[k] = fmaf(fmaxf(a[k].y + (vv).y, 0.f), wv.y, s[k]);      \
      s[k] = fmaf(fmaxf(a[k].z + (vv).z, 0.f), wv.z, s[k]);      \
      s[k] = fmaf(fmaxf(a[k].w + (vv).w, 0.f), wv.w, s[k]);      \
    }                                                            \
  }

  // two 7-deep batches: 7 loads in flight, then compute (cold-HBM tolerant)
  float4 vv[7];
  #pragma unroll
  for (int j = 0; j < 7; ++j) vv[j] = vp[j * (HID / 4)];
  #pragma unroll
  for (int j = 0; j < 7; ++j) PAIR_BODY(vv[j]);
  #pragma unroll
  for (int j = 0; j < 7; ++j) vv[j] = vp[(7 + j) * (HID / 4)];
  #pragma unroll
  for (int j = 0; j < 7; ++j) PAIR_BODY(vv[j]);
#undef PAIR_BODY

  // collapse rows (13 adds), then one 6-step wave reduce
  float t = 0.0f;
  #pragma unroll
  for (int k = 0; k < ROWS; ++k) t += s[k];
  #pragma unroll
  for (int off = 32; off > 0; off >>= 1) t += __shfl_down(t, off);

  __shared__ float sred[4];
  if (lane == 0) sred[w] = t;
  __syncthreads();
  if (threadIdx.x == 0)
    atomicAdd(&out[b], sred[0] + sred[1] + sred[2] + sred[3]);  // 392 total
}

extern "C" void kernel_launch(void* const* d_in, const int* in_sizes, int n_in,
                              void* d_out, int out_size, void* d_ws, size_t ws_size,
                              hipStream_t stream) {
  const float* f1 = (const float*)d_in[0];   // [B, C, 14, 14]
  const float* f2 = (const float*)d_in[1];
  const float* W1 = (const float*)d_in[2];   // [2C, HID]
  const float* b1 = (const float*)d_in[3];   // [HID]
  const float* W2 = (const float*)d_in[4];   // [HID, 1]
  const float* b2 = (const float*)d_in[5];   // [1]
  float* out = (float*)d_out;                // [B, 1]

  float* p1 = (float*)d_ws;
  float* p2 = p1 + P_ELEMS;

  dim3 g1(NLT * NNT, 2);                     // (49 x 8 tiles, 2 sides) = 784
  gemm_p_mfma<<<g1, 256, 0, stream>>>(f1, f2, W1, b1, b2, p1, p2, out);

  pair_kernel<<<PAIR_BLOCKS, 256, 0, stream>>>(p1, p2, W2, out);
}

// Round 12
// 27.107 us; speedup vs baseline: 1.3797x; 1.1692x over previous
//
#include <hip/hip_runtime.h>

typedef __attribute__((ext_vector_type(8))) short bf16x8;
typedef __attribute__((ext_vector_type(4))) float f32x4;

#define C_DIM 512
#define HID   256
#define B_DIM 8
#define L_DIM 196
#define MTPB  7                 // m-tiles per batch (7*32 = 224 >= 196, tail masked)
#define NT    32                // n cols per tile
#define NNT   (HID/NT)          // 8 n-tiles
#define GEMM_BLOCKS (B_DIM*MTPB*NNT*2)      // 896 = 112*8
#define ROWS  14                // i-rows per wave (phase 2)
#define NJC   14                // j-chunks (phase 2)
#define JCL   (L_DIM/NJC)       // 14
#define PAIR_BLOCKS ((B_DIM*NJC*ROWS)/4)    // 392 = 49*8
#define P_ELEMS (B_DIM*L_DIM*HID)

// f32 -> bf16 bits, round-to-nearest (ties up): 2 VALU ops
__device__ __forceinline__ short bf16r(float x) {
  unsigned u = __builtin_bit_cast(unsigned, x);
  return (short)((u + 0x8000u) >> 16);
}

// Phase 1 v4: MFMA bf16, K-split x4, XCD-local per batch.
//   p[b,l,h] = sum_c f[b,c,l] * W[c,h]   (+ b1[h] for side 0)
// wgid = idx*8 + b  ->  all blocks of batch b on XCD b (round-robin dispatch).
// Block = 4 waves = 4 k-quarters of one 32m x 32n tile; LDS tree-combine.
__global__ __launch_bounds__(256) void gemm_p_mfma(
    const float* __restrict__ f1, const float* __restrict__ f2,
    const float* __restrict__ W1, const float* __restrict__ b1,
    const float* __restrict__ b2,
    float* __restrict__ p1, float* __restrict__ p2,
    float* __restrict__ out) {
  // init output accumulators (pair_kernel atomicAdds into them)
  if (blockIdx.x == 0 && threadIdx.x < B_DIM)
    out[threadIdx.x] = (float)(L_DIM * L_DIM) * b2[0];

  const int wgid = blockIdx.x;                  // 0..895
  const int b    = wgid & 7;                    // XCD-co-located batch
  const int idx  = wgid >> 3;                   // 0..111
  const int nt   = idx & 7;                     // n-tile 0..7
  const int ms   = idx >> 3;                    // 0..13
  const int side = ms & 1;
  const int mt   = ms >> 1;                     // m-tile within b, 0..6

  const float* __restrict__ f = side ? f2 : f1;
  const float* __restrict__ W = W1 + side * C_DIM * HID;
  float* __restrict__ p = side ? p2 : p1;

  const int tid  = threadIdx.x;
  const int kq   = tid >> 6;                    // wave = k-quarter 0..3
  const int lane = tid & 63;
  const int g    = lane >> 4;                   // k-subgroup 0..3
  const int mcol = lane & 15;

  // A row bases within batch b (tail rows >=196 clamped, masked at store)
  int aoff[2];
  #pragma unroll
  for (int mi = 0; mi < 2; ++mi) {
    const int rib = mt * 32 + mi * 16 + mcol;   // 0..223
    const int l = rib < L_DIM ? rib : L_DIM - 1;
    aoff[mi] = (b * C_DIM) * L_DIM + l;
  }
  const int h0 = nt * NT + mcol;                // + ni*16

  f32x4 acc[2][2];
  #pragma unroll
  for (int mi = 0; mi < 2; ++mi)
    #pragma unroll
    for (int ni = 0; ni < 2; ++ni)
      acc[mi][ni] = (f32x4){0.f, 0.f, 0.f, 0.f};

  #pragma unroll
  for (int ks = 0; ks < 4; ++ks) {
    const int k0 = kq * 128 + ks * 32 + g * 8;  // this lane's 8 k's
    bf16x8 afr[2], bfr[2];
    #pragma unroll
    for (int mi = 0; mi < 2; ++mi) {
      const float* __restrict__ pa = f + aoff[mi] + k0 * L_DIM;
      #pragma unroll
      for (int i = 0; i < 8; ++i) afr[mi][i] = bf16r(pa[i * L_DIM]);
    }
    #pragma unroll
    for (int ni = 0; ni < 2; ++ni) {
      const float* __restrict__ pb = W + k0 * HID + h0 + ni * 16;
      #pragma unroll
      for (int i = 0; i < 8; ++i) bfr[ni][i] = bf16r(pb[i * HID]);
    }
    #pragma unroll
    for (int mi = 0; mi < 2; ++mi)
      #pragma unroll
      for (int ni = 0; ni < 2; ++ni)
        acc[mi][ni] = __builtin_amdgcn_mfma_f32_16x16x32_bf16(
            afr[mi], bfr[ni], acc[mi][ni], 0, 0, 0);
  }

  // tree-combine 4 k-quarter waves (flattened idx = mi*8 + ni*4 + reg)
  __shared__ float comb[2][64][17];             // 8.7 KB, 17-stride
  if (kq >= 2) {
    #pragma unroll
    for (int mi = 0; mi < 2; ++mi)
      #pragma unroll
      for (int ni = 0; ni < 2; ++ni)
        *(float4*)&comb[kq - 2][lane][mi * 8 + ni * 4] =
            *(float4*)&acc[mi][ni];
  }
  __syncthreads();
  if (kq < 2) {
    #pragma unroll
    for (int mi = 0; mi < 2; ++mi)
      #pragma unroll
      for (int ni = 0; ni < 2; ++ni) {
        const float4 o = *(const float4*)&comb[kq][lane][mi * 8 + ni * 4];
        acc[mi][ni][0] += o.x; acc[mi][ni][1] += o.y;
        acc[mi][ni][2] += o.z; acc[mi][ni][3] += o.w;
      }
  }
  __syncthreads();
  if (kq == 1) {
    #pragma unroll
    for (int mi = 0; mi < 2; ++mi)
      #pragma unroll
      for (int ni = 0; ni < 2; ++ni)
        *(float4*)&comb[0][lane][mi * 8 + ni * 4] = *(float4*)&acc[mi][ni];
  }
  __syncthreads();
  if (kq == 0) {
    // C/D layout (verified): col = lane&15, row = g*4 + reg
    #pragma unroll
    for (int mi = 0; mi < 2; ++mi) {
      const int rib0 = mt * 32 + mi * 16 + g * 4;
      #pragma unroll
      for (int ni = 0; ni < 2; ++ni) {
        const int h = h0 + ni * 16;
        const float bias = side ? 0.0f : b1[h];
        const float4 o = *(const float4*)&comb[0][lane][mi * 8 + ni * 4];
        const float v0 = acc[mi][ni][0] + o.x + bias;
        const float v1 = acc[mi][ni][1] + o.y + bias;
        const float v2 = acc[mi][ni][2] + o.z + bias;
        const float v3 = acc[mi][ni][3] + o.w + bias;
        // tail mask (only mt=6 has rows >=196)
        if (rib0 + 0 < L_DIM) p[(b * L_DIM + rib0 + 0) * HID + h] = v0;
        if (rib0 + 1 < L_DIM) p[(b * L_DIM + rib0 + 1) * HID + h] = v1;
        if (rib0 + 2 < L_DIM) p[(b * L_DIM + rib0 + 2) * HID + h] = v2;
        if (rib0 + 3 < L_DIM) p[(b * L_DIM + rib0 + 3) * HID + h] = v3;
      }
    }
  }
}

// Phase 2 (r11 body, XCD-local): wgid = idx*8 + b -> all 49 blocks of batch b
// on XCD b (p1[b]/p2[b] stay L2-local; atomics XCD-local).
// wave = 14 i-rows x one 14-j chunk; block-sum -> ONE atomicAdd into out[b].
__global__ __launch_bounds__(256) void pair_kernel(
    const float* __restrict__ p1, const float* __restrict__ p2,
    const float* __restrict__ W2, float* __restrict__ out) {
  const int lane = threadIdx.x & 63;
  const int w    = threadIdx.x >> 6;
  const int b    = blockIdx.x & 7;              // XCD-co-located batch
  const int idx  = blockIdx.x >> 3;             // 0..48
  const int r4   = idx * 4 + w;                 // 0..195
  const int jc   = r4 / ROWS;                   // 0..13
  const int wi   = r4 % ROWS;                   // 0..13

  const float4 wv = *(const float4*)(W2 + lane * 4);
  const float* __restrict__ p1b = p1 + (b * L_DIM) * HID + lane * 4;

  float4 a[ROWS];
  #pragma unroll
  for (int k = 0; k < ROWS; ++k)
    a[k] = *(const float4*)(p1b + (wi + k * ROWS) * HID);  // i = wi + k*14

  float s[ROWS];
  #pragma unroll
  for (int k = 0; k < ROWS; ++k) s[k] = 0.0f;

  const float4* __restrict__ vp =
      (const float4*)(p2 + (b * L_DIM + jc * JCL) * HID) + lane;

#define PAIR_BODY(vv)                                            \
  {                                                              \
    _Pragma("unroll")                                            \
    for (int k = 0; k < ROWS; ++k) {                             \
      s[k] = fmaf(fmaxf(a[k].x + (vv).x, 0.f), wv.x, s[k]);      \
      s[k] = fmaf(fmaxf(a[k].y + (vv).y, 0.f), wv.y, s[k]);      \
      s[k] = fmaf(fmaxf(a[k].z + (vv).z, 0.f), wv.z, s[k]);      \
      s[k] = fmaf(fmaxf(a[k].w + (vv).w, 0.f), wv.w, s[k]);      \
    }                                                            \
  }

  // two 7-deep batches: 7 loads in flight, then compute
  float4 vv[7];
  #pragma unroll
  for (int j = 0; j < 7; ++j) vv[j] = vp[j * (HID / 4)];
  #pragma unroll
  for (int j = 0; j < 7; ++j) PAIR_BODY(vv[j]);
  #pragma unroll
  for (int j = 0; j < 7; ++j) vv[j] = vp[(7 + j) * (HID / 4)];
  #pragma unroll
  for (int j = 0; j < 7; ++j) PAIR_BODY(vv[j]);
#undef PAIR_BODY

  // collapse rows (13 adds), then one 6-step wave reduce
  float t = 0.0f;
  #pragma unroll
  for (int k = 0; k < ROWS; ++k) t += s[k];
  #pragma unroll
  for (int off = 32; off > 0; off >>= 1) t += __shfl_down(t, off);

  __shared__ float sred[4];
  if (lane == 0) sred[w] = t;
  __syncthreads();
  if (threadIdx.x == 0)
    atomicAdd(&out[b], sred[0] + sred[1] + sred[2] + sred[3]);  // 392 total
}

extern "C" void kernel_launch(void* const* d_in, const int* in_sizes, int n_in,
                              void* d_out, int out_size, void* d_ws, size_t ws_size,
                              hipStream_t stream) {
  const float* f1 = (const float*)d_in[0];   // [B, C, 14, 14]
  const float* f2 = (const float*)d_in[1];
  const float* W1 = (const float*)d_in[2];   // [2C, HID]
  const float* b1 = (const float*)d_in[3];   // [HID]
  const float* W2 = (const float*)d_in[4];   // [HID, 1]
  const float* b2 = (const float*)d_in[5];   // [1]
  float* out = (float*)d_out;                // [B, 1]

  float* p1 = (float*)d_ws;
  float* p2 = p1 + P_ELEMS;

  gemm_p_mfma<<<GEMM_BLOCKS, 256, 0, stream>>>(f1, f2, W1, b1, b2, p1, p2, out);

  pair_kernel<<<PAIR_BLOCKS, 256, 0, stream>>>(p1, p2, W2, out);
}